// Round 12
// baseline (254.902 us; speedup 1.0000x reference)
//
#include <hip/hip_runtime.h>
#include <hip/hip_bf16.h>
#include <hip/hip_fp16.h>
#include <math.h>

// ---------------------------------------------------------------------------
// Diffusion renoise-loop + conditional MLP loss, MI355X (gfx950).
// RNG: threefry_partitionable (bit-exact, absmax 0.0 rounds 1-11).
// Round 12: the renoise loop is DECOUPLED PER POINT: state s_k(p) depends only
// on (p,k), and matched points stay matched, so m_p = first matching state.
// k_renoise is now ONE flat GEMM-rowmax over 8 states x 256 points x 1024
// candidates per block -- no iteration barriers, no compaction, no atomics in
// the hot loop (round 11 was serialization/tail-bound: all pipes ~half idle).
// cnt_k = #{p: m_p > k}; kstar gate in k_loss unchanged (validated).
#define BS   128
#define NS   1024
#define HID  512
#define CTX  128
#define TT   100
#define ITERS 8

// ---- workspace layout (bytes) ---------------------------------------------
constexpr size_t OFF_SACP  = 0;         // 100 f32
constexpr size_t OFF_S1M   = 512;       // 100 f32
constexpr size_t OFF_KEYS  = 1024;      // 16 u32
constexpr size_t OFF_CNTG  = 1152;      // u32[8][512] -> 17536
constexpr size_t OFF_MASK  = 17536;     // u8[131072] -> 148608
constexpr size_t OFF_BIAS  = 262144;    // f32[128*512] -> 524288
constexpr size_t OFF_PA    = 524288;    // float4[512] -> 532480
constexpr size_t OFF_PB    = 532480;    // float4[512] -> 540672
constexpr size_t OFF_PC    = 540672;    // f32[512]   -> 542720
constexpr size_t OFF_PART  = 542720;    // f32[512]   -> 544768 (~0.55 MB)

typedef __attribute__((ext_vector_type(8))) _Float16 half8;
typedef __attribute__((ext_vector_type(4))) float f32x4;

// ---- threefry2x32-20 -------------------------------------------------------
__device__ __forceinline__ unsigned rotl32(unsigned x, int r) {
  return (x << r) | (x >> (32 - r));
}
__device__ __forceinline__ void tf2x32(unsigned k0, unsigned k1,
                                       unsigned x0, unsigned x1,
                                       unsigned& o0, unsigned& o1) {
  unsigned k2 = k0 ^ k1 ^ 0x1BD11BDAu;
  x0 += k0; x1 += k1;
#define TF_R4(a,b,c,d) \
  x0 += x1; x1 = rotl32(x1,(a)); x1 ^= x0; \
  x0 += x1; x1 = rotl32(x1,(b)); x1 ^= x0; \
  x0 += x1; x1 = rotl32(x1,(c)); x1 ^= x0; \
  x0 += x1; x1 = rotl32(x1,(d)); x1 ^= x0;
  TF_R4(13,15,26,6)   x0 += k1; x1 += k2 + 1u;
  TF_R4(17,29,16,24)  x0 += k2; x1 += k0 + 2u;
  TF_R4(13,15,26,6)   x0 += k0; x1 += k1 + 3u;
  TF_R4(17,29,16,24)  x0 += k1; x1 += k2 + 4u;
  TF_R4(13,15,26,6)   x0 += k2; x1 += k0 + 5u;
#undef TF_R4
  o0 = x0; o1 = x1;
}

__device__ __forceinline__ float bits_to_u(unsigned bits) {
  float f = __uint_as_float((bits >> 9) | 0x3f800000u) - 1.0f;
  float u = f * 2.0f + (-0.99999994f);
  return fmaxf(-0.99999994f, u);
}

__device__ __forceinline__ float nrm_from_idx(unsigned k0, unsigned k1, unsigned idx) {
  unsigned o0, o1;
  tf2x32(k0, k1, 0u, idx, o0, o1);
  return 1.41421356f * erfinvf(bits_to_u(o0 ^ o1));
}

__device__ __forceinline__ float ftanh(float x) {
  float e = __expf(2.0f * x);
  float r = __builtin_amdgcn_rcpf(e + 1.0f);
  return fmaf(-2.0f, r, 1.0f);
}

// fp16 hi/lo split: x ~= hi + lo with |err| <~ 2^-23 |x|
__device__ __forceinline__ void split16(float x, unsigned short& hi, unsigned short& lo) {
  __half h = __float2half(x);
  float hf = __half2float(h);
  __half l = __float2half(x - hf);
  hi = __half_as_ushort(h);
  lo = __half_as_ushort(l);
}
__device__ __forceinline__ unsigned pack2(unsigned short a, unsigned short b) {
  return (unsigned)a | ((unsigned)b << 16);
}

// ---- kernel 1: setup — blocks 0..255 bias, 256 weight pack, 257 tables -----
__global__ __launch_bounds__(256) void k_setup(
    const float* __restrict__ ctx, const float* __restrict__ Wc,
    const float* __restrict__ Wt, const float* __restrict__ b1,
    const int* __restrict__ ts, float* __restrict__ biasb,
    const float* __restrict__ W1, const float* __restrict__ W2,
    float4* __restrict__ PA, float4* __restrict__ PB, float* __restrict__ PC,
    float* __restrict__ sacp, float* __restrict__ s1m,
    unsigned* __restrict__ keys) {
  if (blockIdx.x == 257) {
    __shared__ double omb[TT];
    int t = threadIdx.x;
    if (t < TT) {
      const double PI = 3.14159265358979323846;
      double t0 = (double)t / TT, t1 = (double)(t + 1) / TT;
      double c0 = cos((t0 + 0.008) / 1.008 * PI * 0.5); double ab0 = c0 * c0;
      double c1 = cos((t1 + 0.008) / 1.008 * PI * 0.5); double ab1 = c1 * c1;
      double beta = 1.0 - ab1 / ab0;
      if (beta > 0.999) beta = 0.999;
      omb[t] = 1.0 - beta;
    }
    __syncthreads();
    if (t < TT) {
      double acp = 1.0;
      for (int i = 0; i <= t; ++i) acp *= omb[i];
      sacp[t] = (float)sqrt(acp);
      s1m[t]  = (float)sqrt(1.0 - acp);
    }
    if (t >= 128 && t < 128 + ITERS) {
      int k = t - 128;
      unsigned o0, o1;
      tf2x32(0u, 42u, 0u, (unsigned)k, o0, o1);
      keys[2*k] = o0; keys[2*k+1] = o1;
    }
    return;
  }
  if (blockIdx.x == 256) {
    for (int j = threadIdx.x; j < HID; j += 256) {
      PA[j] = make_float4(W1[j], W1[512 + j], W1[1024 + j], W1[1536 + j]);
      PB[j] = make_float4(W1[2048 + j], W1[2560 + j], W2[j*6 + 3], W2[j*6 + 4]);
      PC[j] = W2[j*6 + 5];
    }
    return;
  }
  __shared__ float sc[CTX];
  int b = blockIdx.x >> 1;
  int j = (blockIdx.x & 1) * 256 + (int)threadIdx.x;
  if (threadIdx.x < CTX) sc[threadIdx.x] = ctx[(size_t)b * CTX + threadIdx.x];
  __syncthreads();
  float acc = 0.f;
  for (int q = 0; q < CTX; ++q) acc = fmaf(sc[q], Wc[q * HID + j], acc);
  float temb = (float)ts[b] / 100.0f;
  biasb[b * HID + j] = acc + temb * Wt[j] + b1[j];
}

// ---- kernel 2: flat renoise — 512 blocks (4 q-slices x 128 batches) --------
// Block: 256 points x 8 states = 128 query tiles; 4 waves x 32 tiles.
// One pass: rowmax(state s of point p) vs diag -> mism[s][p]; m_p = first
// match; mask = (1<<m_p)-1; cnt_k = #{m_p > k}. No iteration barriers.
__global__ __launch_bounds__(256, 2) void k_renoise(
    const float* __restrict__ data, const float* __restrict__ noise0,
    const int* __restrict__ ts, const float* __restrict__ sacp,
    const float* __restrict__ s1m, const unsigned* __restrict__ keys,
    unsigned* __restrict__ cntg, unsigned char* __restrict__ maskg) {
  __shared__ unsigned stw[10240];          // 40 KB: 1024 records x 10 words
  __shared__ float fdat0[256][4];          // 4 KB: d0,d1,d2 per local point
  __shared__ float zny[8][256][3];         // 24 KB: noisy3-5 per (state,point)
  __shared__ float sdw[4][4][16];          // 1 KB per-wave diag scratch
  __shared__ unsigned char mism[8][256];   // 2 KB
  __shared__ unsigned cnt[8];
  const int b = blockIdx.x & 127, qb = blockIdx.x >> 7;
  const int tid = (int)threadIdx.x;
  const int wv = tid >> 6, lane = tid & 63;
  const int c15 = lane & 15, quad = lane >> 4;
  const int n0 = qb * 256;
  const int t = ts[b];
  const float aa = sacp[t], ssv = s1m[t];
  if (tid < ITERS) cnt[tid] = 0u;
  // ---- fdat0: conditioned dims of this block's 256 points ------------------
  {
    int p = (b << 10) + n0 + tid;
    const float* dp = data + (size_t)p * 6;
    fdat0[tid][0] = dp[0]; fdat0[tid][1] = dp[1]; fdat0[tid][2] = dp[2];
  }
  // ---- dedup candidate panel (full batch, 1024 records, stride 10) ---------
  for (int ii = 0; ii < 4; ++ii) {
    int c = ii * 256 + tid;
    const float2* dp2 = (const float2*)(data + ((size_t)(b << 10) + c) * 6);
    float2 v0 = dp2[0], v1 = dp2[1], v2 = dp2[2];
    float dd[6] = {v0.x, v0.y, v1.x, v1.y, v2.x, v2.y};
    float dsq = dd[0]*dd[0];
    dsq = fmaf(dd[1], dd[1], dsq); dsq = fmaf(dd[2], dd[2], dsq);
    dsq = fmaf(dd[3], dd[3], dsq); dsq = fmaf(dd[4], dd[4], dsq);
    dsq = fmaf(dd[5], dd[5], dsq);
    unsigned U[6];
#pragma unroll
    for (int d = 0; d < 6; ++d) {
      unsigned short hi, lo; split16(dd[d], hi, lo);
      U[d] = pack2(hi, lo);
    }
    unsigned short vh, vl; split16(-0.5f * dsq, vh, vl);
    unsigned* rec = stw + c * 10;
    *(uint2*)(rec + 0) = make_uint2(U[0], U[1]);
    *(uint2*)(rec + 2) = make_uint2(U[2], U[3]);
    *(uint2*)(rec + 4) = make_uint2(U[4], U[5]);
    *(uint2*)(rec + 6) = make_uint2(pack2(vh, vl), 0u);
  }
  // ---- precompute all 8 noisy states (full-width parallel) -----------------
  for (int i = 0; i < 8; ++i) {
    int idx = i * 256 + tid;       // (s, lp)
    int s = idx >> 8, lp = idx & 255;
    int p = (b << 10) + n0 + lp;
    unsigned base6 = (unsigned)p * 6u;
    float z3, z4, z5;
    if (s == 0) {
      const float* np0 = noise0 + (size_t)p * 6;
      z3 = np0[3]; z4 = np0[4]; z5 = np0[5];
    } else {
      unsigned kk0 = keys[2*(s-1)], kk1 = keys[2*(s-1)+1];
      z3 = nrm_from_idx(kk0, kk1, base6 + 3u);
      z4 = nrm_from_idx(kk0, kk1, base6 + 4u);
      z5 = nrm_from_idx(kk0, kk1, base6 + 5u);
    }
    const float* dp = data + (size_t)p * 6;
    zny[s][lp][0] = __fadd_rn(__fmul_rn(aa, dp[3]), __fmul_rn(ssv, z3));
    zny[s][lp][1] = __fadd_rn(__fmul_rn(aa, dp[4]), __fmul_rn(ssv, z4));
    zny[s][lp][2] = __fadd_rn(__fmul_rn(aa, dp[5]), __fmul_rn(ssv, z5));
  }
  __syncthreads();
  // ---- flat sweep: wave wv owns states {2wv, 2wv+1}; 8 groups of 4 tiles ---
  const int abase = c15 * 10 + quad * 2;
  for (int qg = 0; qg < 8; ++qg) {
    int s = 2 * wv + (qg >> 2);
    // build bq[4]: tile j covers points pg_j*16..+15 at state s
    half8 bq[4];
#pragma unroll
    for (int j = 0; j < 4; ++j) {
      int lp = ((qg & 3) * 4 + j) * 16 + c15;
      uint4 wds = make_uint4(0u, 0u, 0u, 0u);
      if (quad < 3) {
        float f0, f1;
        if (quad == 0)      { f0 = fdat0[lp][0]; f1 = fdat0[lp][1]; }
        else if (quad == 1) { f0 = fdat0[lp][2]; f1 = zny[s][lp][0]; }
        else                { f0 = zny[s][lp][1]; f1 = zny[s][lp][2]; }
        unsigned short h, lo2;
        split16(f0, h, lo2); wds.x = pack2(h, h); wds.y = pack2(lo2, lo2);
        split16(f1, h, lo2); wds.z = pack2(h, h); wds.w = pack2(lo2, lo2);
      } else {
        wds.x = 0x3C003C00u;  // ones in the dsq slot; words 13..15 stay 0
      }
      bq[j] = __builtin_bit_cast(half8, wds);
    }
    // diag via gathered-A rows (bit-identical column dot products)
#pragma unroll
    for (int j = 0; j < 4; ++j) {
      int row = n0 + ((qg & 3) * 4 + j) * 16 + c15;
      uint2 u = *(const uint2*)(stw + row * 10 + quad * 2);
      half8 ag = __builtin_bit_cast(half8, make_uint4(u.x, u.x, u.y, u.y));
      f32x4 z = {0.f, 0.f, 0.f, 0.f};
      f32x4 dacc = __builtin_amdgcn_mfma_f32_16x16x32_f16(ag, bq[j], z, 0, 0, 0);
      if ((c15 >> 2) == quad) sdw[wv][j][c15] = dacc[c15 & 3];
    }
    // sweep all 64 candidate tiles, chunks of 4 with register dbuf prefetch
    float bv0 = -__builtin_inff(), bv1 = -__builtin_inff();
    float bv2 = -__builtin_inff(), bv3 = -__builtin_inff();
    uint2 cu[4], cun[4];
#pragma unroll
    for (int cc = 0; cc < 4; ++cc)
      cu[cc] = *(const uint2*)(stw + cc * 160 + abase);
    for (int ctc = 0; ctc < 16; ++ctc) {
      if (ctc < 15) {
#pragma unroll
        for (int cc = 0; cc < 4; ++cc)
          cun[cc] = *(const uint2*)(stw + ((ctc + 1) * 4 + cc) * 160 + abase);
      }
#pragma unroll
      for (int cc = 0; cc < 4; ++cc) {
        half8 ac = __builtin_bit_cast(half8,
                     make_uint4(cu[cc].x, cu[cc].x, cu[cc].y, cu[cc].y));
        f32x4 z = {0.f, 0.f, 0.f, 0.f};
        f32x4 a0 = __builtin_amdgcn_mfma_f32_16x16x32_f16(ac, bq[0], z, 0, 0, 0);
        f32x4 a1 = __builtin_amdgcn_mfma_f32_16x16x32_f16(ac, bq[1], z, 0, 0, 0);
        f32x4 a2 = __builtin_amdgcn_mfma_f32_16x16x32_f16(ac, bq[2], z, 0, 0, 0);
        f32x4 a3 = __builtin_amdgcn_mfma_f32_16x16x32_f16(ac, bq[3], z, 0, 0, 0);
        bv0 = fmaxf(fmaxf(bv0, fmaxf(fmaxf(a0[0], a0[1]), a0[2])), a0[3]);
        bv1 = fmaxf(fmaxf(bv1, fmaxf(fmaxf(a1[0], a1[1]), a1[2])), a1[3]);
        bv2 = fmaxf(fmaxf(bv2, fmaxf(fmaxf(a2[0], a2[1]), a2[2])), a2[3]);
        bv3 = fmaxf(fmaxf(bv3, fmaxf(fmaxf(a3[0], a3[1]), a3[2])), a3[3]);
      }
      if (ctc < 15) {
#pragma unroll
        for (int cc = 0; cc < 4; ++cc) cu[cc] = cun[cc];
      }
    }
    // combine across quads (full rowmax per query col)
    bv0 = fmaxf(bv0, __shfl_xor(bv0, 16)); bv0 = fmaxf(bv0, __shfl_xor(bv0, 32));
    bv1 = fmaxf(bv1, __shfl_xor(bv1, 16)); bv1 = fmaxf(bv1, __shfl_xor(bv1, 32));
    bv2 = fmaxf(bv2, __shfl_xor(bv2, 16)); bv2 = fmaxf(bv2, __shfl_xor(bv2, 32));
    bv3 = fmaxf(bv3, __shfl_xor(bv3, 16)); bv3 = fmaxf(bv3, __shfl_xor(bv3, 32));
    // owner lanes (quad 0): mism[s][point] = rowmax > diag
    if (quad == 0) {
      mism[s][((qg & 3) * 4 + 0) * 16 + c15] = (bv0 > sdw[wv][0][c15]) ? 1 : 0;
      mism[s][((qg & 3) * 4 + 1) * 16 + c15] = (bv1 > sdw[wv][1][c15]) ? 1 : 0;
      mism[s][((qg & 3) * 4 + 2) * 16 + c15] = (bv2 > sdw[wv][2][c15]) ? 1 : 0;
      mism[s][((qg & 3) * 4 + 3) * 16 + c15] = (bv3 > sdw[wv][3][c15]) ? 1 : 0;
    }
  }
  __syncthreads();
  // ---- per point: m_p = first matching state; mask; cnt_k ------------------
  int mp = 8;
#pragma unroll
  for (int s = 0; s < 8; ++s) {
    if (mp == 8 && mism[s][tid] == 0) mp = s;
  }
  maskg[(b << 10) + n0 + tid] = (unsigned char)((1u << mp) - 1u);
#pragma unroll
  for (int k = 0; k < ITERS; ++k) {
    unsigned long long mk = __ballot(mp > k ? 1 : 0);
    if (lane == 0) atomicAdd(&cnt[k], (unsigned)__popcll(mk));
  }
  __syncthreads();
  if (tid < ITERS) cntg[tid * 512 + (int)blockIdx.x] = cnt[tid];
}

// ---- kernel 3: MLP + masked SE, with fused finalize (exact cont gate) ------
__global__ __launch_bounds__(256) void k_loss(
    const float* __restrict__ data, const float* __restrict__ noise0,
    const int* __restrict__ ts, const float* __restrict__ sacp,
    const float* __restrict__ s1m, const unsigned* __restrict__ keys,
    const unsigned* __restrict__ cntg, const unsigned char* __restrict__ maskg,
    const float* __restrict__ biasb,
    const float4* __restrict__ PA, const float4* __restrict__ PB,
    const float* __restrict__ PC, const float* __restrict__ b2,
    float* __restrict__ part) {
  __shared__ float4 sA[HID];
  __shared__ float4 sB[HID];
  __shared__ float2 sCb[HID];
  __shared__ float zn[256][6];     // z3..z5, noisy3..5 per local point
  __shared__ float pp[4][3][256];  // per-wave partials
  __shared__ float red[4];
  __shared__ int ksh;
  int b = blockIdx.x >> 2, qq = blockIdx.x & 3;
  int tid = (int)threadIdx.x;
  int wv = tid >> 6, lane = tid & 63;
  // ---- phase 1: kstar from cntg --------------------------------------------
  if (tid < 64) {
    int ks = ITERS;
    for (int k2 = 0; k2 < ITERS; ++k2) {
      unsigned v = 0u;
#pragma unroll
      for (int i = 0; i < 8; ++i) v += cntg[k2 * 512 + i * 64 + tid];
#pragma unroll
      for (int m = 32; m >= 1; m >>= 1) v += (unsigned)__shfl_xor((int)v, m);
      if (v < 10u && ks == ITERS) ks = k2;  // first failing iteration
    }
    if (tid == 0) ksh = ks;
  }
  // stage weights meanwhile
  for (int j = tid; j < HID; j += 256) {
    sA[j] = PA[j]; sB[j] = PB[j];
    sCb[j] = make_float2(PC[j], biasb[(size_t)b * HID + j]);
  }
  __syncthreads();
  // ---- phase 2: finalize this block's 256 points (1 per thread) ------------
  int p0 = (b << 10) + qq * 256;
  {
    int kstar = ksh;
    unsigned gate = (kstar >= ITERS) ? 0xFFu : ((1u << kstar) - 1u);
    int p = p0 + tid;
    int t = ts[b];
    float aa = sacp[t], ssv = s1m[t];
    unsigned m = (unsigned)maskg[p] & gate;
    float z3, z4, z5;
    if (m) {
      int j = 31 - __clz((int)m);  // last applied renoise iteration
      unsigned base6 = (unsigned)p * 6u;
      unsigned kk0 = keys[2*j], kk1 = keys[2*j+1];
      z3 = nrm_from_idx(kk0, kk1, base6 + 3u);
      z4 = nrm_from_idx(kk0, kk1, base6 + 4u);
      z5 = nrm_from_idx(kk0, kk1, base6 + 5u);
    } else {
      const float* np0 = noise0 + (size_t)p * 6;
      z3 = np0[3]; z4 = np0[4]; z5 = np0[5];
    }
    const float* dp = data + (size_t)p * 6;
    zn[tid][0] = z3; zn[tid][1] = z4; zn[tid][2] = z5;
    zn[tid][3] = __fadd_rn(__fmul_rn(aa, dp[3]), __fmul_rn(ssv, z3));
    zn[tid][4] = __fadd_rn(__fmul_rn(aa, dp[4]), __fmul_rn(ssv, z4));
    zn[tid][5] = __fadd_rn(__fmul_rn(aa, dp[5]), __fmul_rn(ssv, z5));
  }
  __syncthreads();
  // ---- phase 3: MLP, j-loop split across the 4 waves -----------------------
  float x[4][6];
  float a0[4], a1[4], a2[4];
#pragma unroll
  for (int q = 0; q < 4; ++q) {
    int pl = q * 64 + lane;
    int p = p0 + pl;
    x[q][0] = data[p*6+0]; x[q][1] = data[p*6+1]; x[q][2] = data[p*6+2];
    x[q][3] = zn[pl][3]; x[q][4] = zn[pl][4]; x[q][5] = zn[pl][5];
    a0[q] = 0.f; a1[q] = 0.f; a2[q] = 0.f;
  }
  int j0 = wv * 128;
#pragma unroll 2
  for (int jj = 0; jj < 128; ++jj) {
    int j = j0 + jj;
    float4 A = sA[j];
    float4 Bv = sB[j];
    float2 Cb = sCb[j];
#pragma unroll
    for (int q = 0; q < 4; ++q) {
      float s = x[q][0] * A.x;
      s = fmaf(x[q][1], A.y, s); s = fmaf(x[q][2], A.z, s);
      s = fmaf(x[q][3], A.w, s); s = fmaf(x[q][4], Bv.x, s);
      s = fmaf(x[q][5], Bv.y, s);
      s += Cb.y;
      float h = ftanh(s);
      a0[q] = fmaf(h, Bv.z, a0[q]);
      a1[q] = fmaf(h, Bv.w, a1[q]);
      a2[q] = fmaf(h, Cb.x, a2[q]);
    }
  }
#pragma unroll
  for (int q = 0; q < 4; ++q) {
    pp[wv][0][q * 64 + lane] = a0[q];
    pp[wv][1][q * 64 + lane] = a1[q];
    pp[wv][2][q * 64 + lane] = a2[q];
  }
  __syncthreads();
  float f0 = (pp[0][0][tid] + pp[1][0][tid] + pp[2][0][tid] + pp[3][0][tid])
             + b2[3] - zn[tid][0];
  float f1 = (pp[0][1][tid] + pp[1][1][tid] + pp[2][1][tid] + pp[3][1][tid])
             + b2[4] - zn[tid][1];
  float f2 = (pp[0][2][tid] + pp[1][2][tid] + pp[2][2][tid] + pp[3][2][tid])
             + b2[5] - zn[tid][2];
  float lsum = f0 * f0;
  lsum = fmaf(f1, f1, lsum);
  lsum = fmaf(f2, f2, lsum);
#pragma unroll
  for (int off = 32; off > 0; off >>= 1) lsum += __shfl_down(lsum, off);
  if ((tid & 63) == 0) red[tid >> 6] = lsum;
  __syncthreads();
  if (tid == 0) part[blockIdx.x] = red[0] + red[1] + red[2] + red[3];
}

// ---- kernel 4: final reduce ------------------------------------------------
__global__ void k_red(const float* __restrict__ part, float* __restrict__ out) {
  int b = (int)threadIdx.x;
  if (b < BS) {
    out[b] = (part[4*b] + part[4*b+1] + part[4*b+2] + part[4*b+3]) / 3072.0f;
  }
}

// ---------------------------------------------------------------------------
extern "C" void kernel_launch(void* const* d_in, const int* in_sizes, int n_in,
                              void* d_out, int out_size, void* d_ws, size_t ws_size,
                              hipStream_t stream) {
  (void)in_sizes; (void)n_in; (void)out_size; (void)ws_size;
  const float* data    = (const float*)d_in[0];
  const float* context = (const float*)d_in[1];
  const float* noise0  = (const float*)d_in[2];
  const float* W1      = (const float*)d_in[3];
  const float* Wc      = (const float*)d_in[4];
  const float* Wt      = (const float*)d_in[5];
  const float* b1      = (const float*)d_in[6];
  const float* W2      = (const float*)d_in[7];
  const float* b2      = (const float*)d_in[8];
  const int*   ts      = (const int*)d_in[9];
  float* out = (float*)d_out;

  char* w = (char*)d_ws;
  float*    sacp   = (float*)(w + OFF_SACP);
  float*    s1m    = (float*)(w + OFF_S1M);
  unsigned* keys   = (unsigned*)(w + OFF_KEYS);
  unsigned* cntg   = (unsigned*)(w + OFF_CNTG);
  unsigned char* maskg = (unsigned char*)(w + OFF_MASK);
  float*    biasb  = (float*)(w + OFF_BIAS);
  float4*   PA     = (float4*)(w + OFF_PA);
  float4*   PB     = (float4*)(w + OFF_PB);
  float*    PC     = (float*)(w + OFF_PC);
  float*    part   = (float*)(w + OFF_PART);

  k_setup<<<258, 256, 0, stream>>>(context, Wc, Wt, b1, ts, biasb,
                                   W1, W2, PA, PB, PC, sacp, s1m, keys);
  k_renoise<<<512, 256, 0, stream>>>(data, noise0, ts, sacp, s1m, keys,
                                     cntg, maskg);
  k_loss<<<512, 256, 0, stream>>>(data, noise0, ts, sacp, s1m, keys, cntg,
                                  maskg, biasb, PA, PB, PC, b2, part);
  k_red<<<1, 128, 0, stream>>>(part, out);
}

// Round 13
// 177.739 us; speedup vs baseline: 1.4341x; 1.4341x over previous
//
#include <hip/hip_runtime.h>
#include <hip/hip_bf16.h>
#include <hip/hip_fp16.h>
#include <math.h>

// ---------------------------------------------------------------------------
// Diffusion renoise-loop + conditional MLP loss, MI355X (gfx950).
// RNG: threefry_partitionable (bit-exact, absmax 0.0 rounds 1-12).
// Round 13: round-12 flat decoupled-per-point structure (validated) + spill
// fix: #pragma unroll 1 on the constant-trip qg/ctc/zny loops. Round 12's
// qg loop (constant 8 trips) was fully unrolled by the compiler -> one
// 2048-MFMA body -> scratch spill (FETCH 157 MB, WRITE 45 MB = the 148 us).
// Round 11's dynamic trip counts were what accidentally prevented this.
#define BS   128
#define NS   1024
#define HID  512
#define CTX  128
#define TT   100
#define ITERS 8

// ---- workspace layout (bytes) ---------------------------------------------
constexpr size_t OFF_SACP  = 0;         // 100 f32
constexpr size_t OFF_S1M   = 512;       // 100 f32
constexpr size_t OFF_KEYS  = 1024;      // 16 u32
constexpr size_t OFF_CNTG  = 1152;      // u32[8][512] -> 17536
constexpr size_t OFF_MASK  = 17536;     // u8[131072] -> 148608
constexpr size_t OFF_BIAS  = 262144;    // f32[128*512] -> 524288
constexpr size_t OFF_PA    = 524288;    // float4[512] -> 532480
constexpr size_t OFF_PB    = 532480;    // float4[512] -> 540672
constexpr size_t OFF_PC    = 540672;    // f32[512]   -> 542720
constexpr size_t OFF_PART  = 542720;    // f32[512]   -> 544768 (~0.55 MB)

typedef __attribute__((ext_vector_type(8))) _Float16 half8;
typedef __attribute__((ext_vector_type(4))) float f32x4;

// ---- threefry2x32-20 -------------------------------------------------------
__device__ __forceinline__ unsigned rotl32(unsigned x, int r) {
  return (x << r) | (x >> (32 - r));
}
__device__ __forceinline__ void tf2x32(unsigned k0, unsigned k1,
                                       unsigned x0, unsigned x1,
                                       unsigned& o0, unsigned& o1) {
  unsigned k2 = k0 ^ k1 ^ 0x1BD11BDAu;
  x0 += k0; x1 += k1;
#define TF_R4(a,b,c,d) \
  x0 += x1; x1 = rotl32(x1,(a)); x1 ^= x0; \
  x0 += x1; x1 = rotl32(x1,(b)); x1 ^= x0; \
  x0 += x1; x1 = rotl32(x1,(c)); x1 ^= x0; \
  x0 += x1; x1 = rotl32(x1,(d)); x1 ^= x0;
  TF_R4(13,15,26,6)   x0 += k1; x1 += k2 + 1u;
  TF_R4(17,29,16,24)  x0 += k2; x1 += k0 + 2u;
  TF_R4(13,15,26,6)   x0 += k0; x1 += k1 + 3u;
  TF_R4(17,29,16,24)  x0 += k1; x1 += k2 + 4u;
  TF_R4(13,15,26,6)   x0 += k2; x1 += k0 + 5u;
#undef TF_R4
  o0 = x0; o1 = x1;
}

__device__ __forceinline__ float bits_to_u(unsigned bits) {
  float f = __uint_as_float((bits >> 9) | 0x3f800000u) - 1.0f;
  float u = f * 2.0f + (-0.99999994f);
  return fmaxf(-0.99999994f, u);
}

__device__ __forceinline__ float nrm_from_idx(unsigned k0, unsigned k1, unsigned idx) {
  unsigned o0, o1;
  tf2x32(k0, k1, 0u, idx, o0, o1);
  return 1.41421356f * erfinvf(bits_to_u(o0 ^ o1));
}

__device__ __forceinline__ float ftanh(float x) {
  float e = __expf(2.0f * x);
  float r = __builtin_amdgcn_rcpf(e + 1.0f);
  return fmaf(-2.0f, r, 1.0f);
}

// fp16 hi/lo split: x ~= hi + lo with |err| <~ 2^-23 |x|
__device__ __forceinline__ void split16(float x, unsigned short& hi, unsigned short& lo) {
  __half h = __float2half(x);
  float hf = __half2float(h);
  __half l = __float2half(x - hf);
  hi = __half_as_ushort(h);
  lo = __half_as_ushort(l);
}
__device__ __forceinline__ unsigned pack2(unsigned short a, unsigned short b) {
  return (unsigned)a | ((unsigned)b << 16);
}

// ---- kernel 1: setup — blocks 0..255 bias, 256 weight pack, 257 tables -----
__global__ __launch_bounds__(256) void k_setup(
    const float* __restrict__ ctx, const float* __restrict__ Wc,
    const float* __restrict__ Wt, const float* __restrict__ b1,
    const int* __restrict__ ts, float* __restrict__ biasb,
    const float* __restrict__ W1, const float* __restrict__ W2,
    float4* __restrict__ PA, float4* __restrict__ PB, float* __restrict__ PC,
    float* __restrict__ sacp, float* __restrict__ s1m,
    unsigned* __restrict__ keys) {
  if (blockIdx.x == 257) {
    __shared__ double omb[TT];
    int t = threadIdx.x;
    if (t < TT) {
      const double PI = 3.14159265358979323846;
      double t0 = (double)t / TT, t1 = (double)(t + 1) / TT;
      double c0 = cos((t0 + 0.008) / 1.008 * PI * 0.5); double ab0 = c0 * c0;
      double c1 = cos((t1 + 0.008) / 1.008 * PI * 0.5); double ab1 = c1 * c1;
      double beta = 1.0 - ab1 / ab0;
      if (beta > 0.999) beta = 0.999;
      omb[t] = 1.0 - beta;
    }
    __syncthreads();
    if (t < TT) {
      double acp = 1.0;
      for (int i = 0; i <= t; ++i) acp *= omb[i];
      sacp[t] = (float)sqrt(acp);
      s1m[t]  = (float)sqrt(1.0 - acp);
    }
    if (t >= 128 && t < 128 + ITERS) {
      int k = t - 128;
      unsigned o0, o1;
      tf2x32(0u, 42u, 0u, (unsigned)k, o0, o1);
      keys[2*k] = o0; keys[2*k+1] = o1;
    }
    return;
  }
  if (blockIdx.x == 256) {
    for (int j = threadIdx.x; j < HID; j += 256) {
      PA[j] = make_float4(W1[j], W1[512 + j], W1[1024 + j], W1[1536 + j]);
      PB[j] = make_float4(W1[2048 + j], W1[2560 + j], W2[j*6 + 3], W2[j*6 + 4]);
      PC[j] = W2[j*6 + 5];
    }
    return;
  }
  __shared__ float sc[CTX];
  int b = blockIdx.x >> 1;
  int j = (blockIdx.x & 1) * 256 + (int)threadIdx.x;
  if (threadIdx.x < CTX) sc[threadIdx.x] = ctx[(size_t)b * CTX + threadIdx.x];
  __syncthreads();
  float acc = 0.f;
  for (int q = 0; q < CTX; ++q) acc = fmaf(sc[q], Wc[q * HID + j], acc);
  float temb = (float)ts[b] / 100.0f;
  biasb[b * HID + j] = acc + temb * Wt[j] + b1[j];
}

// ---- kernel 2: flat renoise — 512 blocks (4 q-slices x 128 batches) --------
// Block: 256 points x 8 states = 128 query tiles; wave wv owns states
// {2wv,2wv+1}. One pass: rowmax(state s of point p) vs diag -> mism[s][p];
// m_p = first match; mask = (1<<m_p)-1; cnt_k = #{m_p > k}. Two barriers.
// All constant-trip loops around MFMA bodies carry #pragma unroll 1.
__global__ __launch_bounds__(256, 2) void k_renoise(
    const float* __restrict__ data, const float* __restrict__ noise0,
    const int* __restrict__ ts, const float* __restrict__ sacp,
    const float* __restrict__ s1m, const unsigned* __restrict__ keys,
    unsigned* __restrict__ cntg, unsigned char* __restrict__ maskg) {
  __shared__ unsigned stw[10240];          // 40 KB: 1024 records x 10 words
  __shared__ float fdat0[256][4];          // 4 KB: d0,d1,d2 per local point
  __shared__ float zny[8][256][3];         // 24 KB: noisy3-5 per (state,point)
  __shared__ float sdw[4][4][16];          // 1 KB per-wave diag scratch
  __shared__ unsigned char mism[8][256];   // 2 KB
  __shared__ unsigned cnt[8];
  const int b = blockIdx.x & 127, qb = blockIdx.x >> 7;
  const int tid = (int)threadIdx.x;
  const int wv = tid >> 6, lane = tid & 63;
  const int c15 = lane & 15, quad = lane >> 4;
  const int n0 = qb * 256;
  const int t = ts[b];
  const float aa = sacp[t], ssv = s1m[t];
  if (tid < ITERS) cnt[tid] = 0u;
  // ---- fdat0: conditioned dims of this block's 256 points ------------------
  {
    int p = (b << 10) + n0 + tid;
    const float* dp = data + (size_t)p * 6;
    fdat0[tid][0] = dp[0]; fdat0[tid][1] = dp[1]; fdat0[tid][2] = dp[2];
  }
  // ---- dedup candidate panel (full batch, 1024 records, stride 10) ---------
#pragma unroll 1
  for (int ii = 0; ii < 4; ++ii) {
    int c = ii * 256 + tid;
    const float2* dp2 = (const float2*)(data + ((size_t)(b << 10) + c) * 6);
    float2 v0 = dp2[0], v1 = dp2[1], v2 = dp2[2];
    float dd[6] = {v0.x, v0.y, v1.x, v1.y, v2.x, v2.y};
    float dsq = dd[0]*dd[0];
    dsq = fmaf(dd[1], dd[1], dsq); dsq = fmaf(dd[2], dd[2], dsq);
    dsq = fmaf(dd[3], dd[3], dsq); dsq = fmaf(dd[4], dd[4], dsq);
    dsq = fmaf(dd[5], dd[5], dsq);
    unsigned U[6];
#pragma unroll
    for (int d = 0; d < 6; ++d) {
      unsigned short hi, lo; split16(dd[d], hi, lo);
      U[d] = pack2(hi, lo);
    }
    unsigned short vh, vl; split16(-0.5f * dsq, vh, vl);
    unsigned* rec = stw + c * 10;
    *(uint2*)(rec + 0) = make_uint2(U[0], U[1]);
    *(uint2*)(rec + 2) = make_uint2(U[2], U[3]);
    *(uint2*)(rec + 4) = make_uint2(U[4], U[5]);
    *(uint2*)(rec + 6) = make_uint2(pack2(vh, vl), 0u);
  }
  // ---- precompute all 8 noisy states (full-width parallel) -----------------
#pragma unroll 1
  for (int i = 0; i < 8; ++i) {
    int s = i, lp = tid & 255;
    int p = (b << 10) + n0 + lp;
    unsigned base6 = (unsigned)p * 6u;
    float z3, z4, z5;
    if (s == 0) {
      const float* np0 = noise0 + (size_t)p * 6;
      z3 = np0[3]; z4 = np0[4]; z5 = np0[5];
    } else {
      unsigned kk0 = keys[2*(s-1)], kk1 = keys[2*(s-1)+1];
      z3 = nrm_from_idx(kk0, kk1, base6 + 3u);
      z4 = nrm_from_idx(kk0, kk1, base6 + 4u);
      z5 = nrm_from_idx(kk0, kk1, base6 + 5u);
    }
    const float* dp = data + (size_t)p * 6;
    zny[s][lp][0] = __fadd_rn(__fmul_rn(aa, dp[3]), __fmul_rn(ssv, z3));
    zny[s][lp][1] = __fadd_rn(__fmul_rn(aa, dp[4]), __fmul_rn(ssv, z4));
    zny[s][lp][2] = __fadd_rn(__fmul_rn(aa, dp[5]), __fmul_rn(ssv, z5));
  }
  __syncthreads();
  // ---- flat sweep: 8 groups of 4 query tiles -------------------------------
  const int abase = c15 * 10 + quad * 2;
#pragma unroll 1
  for (int qg = 0; qg < 8; ++qg) {
    int s = 2 * wv + (qg >> 2);
    // build bq[4]: tile j covers points ((qg&3)*4+j)*16..+15 at state s
    half8 bq[4];
#pragma unroll
    for (int j = 0; j < 4; ++j) {
      int lp = ((qg & 3) * 4 + j) * 16 + c15;
      uint4 wds = make_uint4(0u, 0u, 0u, 0u);
      if (quad < 3) {
        float f0, f1;
        if (quad == 0)      { f0 = fdat0[lp][0]; f1 = fdat0[lp][1]; }
        else if (quad == 1) { f0 = fdat0[lp][2]; f1 = zny[s][lp][0]; }
        else                { f0 = zny[s][lp][1]; f1 = zny[s][lp][2]; }
        unsigned short h, lo2;
        split16(f0, h, lo2); wds.x = pack2(h, h); wds.y = pack2(lo2, lo2);
        split16(f1, h, lo2); wds.z = pack2(h, h); wds.w = pack2(lo2, lo2);
      } else {
        wds.x = 0x3C003C00u;  // ones in the dsq slot; words 13..15 stay 0
      }
      bq[j] = __builtin_bit_cast(half8, wds);
    }
    // diag via gathered-A rows (bit-identical column dot products)
#pragma unroll
    for (int j = 0; j < 4; ++j) {
      int row = n0 + ((qg & 3) * 4 + j) * 16 + c15;
      uint2 u = *(const uint2*)(stw + row * 10 + quad * 2);
      half8 ag = __builtin_bit_cast(half8, make_uint4(u.x, u.x, u.y, u.y));
      f32x4 z = {0.f, 0.f, 0.f, 0.f};
      f32x4 dacc = __builtin_amdgcn_mfma_f32_16x16x32_f16(ag, bq[j], z, 0, 0, 0);
      if ((c15 >> 2) == quad) sdw[wv][j][c15] = dacc[c15 & 3];
    }
    // sweep all 64 candidate tiles, chunks of 4 with register dbuf prefetch
    float bv0 = -__builtin_inff(), bv1 = -__builtin_inff();
    float bv2 = -__builtin_inff(), bv3 = -__builtin_inff();
    uint2 cu[4], cun[4];
#pragma unroll
    for (int cc = 0; cc < 4; ++cc)
      cu[cc] = *(const uint2*)(stw + cc * 160 + abase);
#pragma unroll 1
    for (int ctc = 0; ctc < 16; ++ctc) {
      if (ctc < 15) {
#pragma unroll
        for (int cc = 0; cc < 4; ++cc)
          cun[cc] = *(const uint2*)(stw + ((ctc + 1) * 4 + cc) * 160 + abase);
      }
#pragma unroll
      for (int cc = 0; cc < 4; ++cc) {
        half8 ac = __builtin_bit_cast(half8,
                     make_uint4(cu[cc].x, cu[cc].x, cu[cc].y, cu[cc].y));
        f32x4 z = {0.f, 0.f, 0.f, 0.f};
        f32x4 a0 = __builtin_amdgcn_mfma_f32_16x16x32_f16(ac, bq[0], z, 0, 0, 0);
        f32x4 a1 = __builtin_amdgcn_mfma_f32_16x16x32_f16(ac, bq[1], z, 0, 0, 0);
        f32x4 a2 = __builtin_amdgcn_mfma_f32_16x16x32_f16(ac, bq[2], z, 0, 0, 0);
        f32x4 a3 = __builtin_amdgcn_mfma_f32_16x16x32_f16(ac, bq[3], z, 0, 0, 0);
        bv0 = fmaxf(fmaxf(bv0, fmaxf(fmaxf(a0[0], a0[1]), a0[2])), a0[3]);
        bv1 = fmaxf(fmaxf(bv1, fmaxf(fmaxf(a1[0], a1[1]), a1[2])), a1[3]);
        bv2 = fmaxf(fmaxf(bv2, fmaxf(fmaxf(a2[0], a2[1]), a2[2])), a2[3]);
        bv3 = fmaxf(fmaxf(bv3, fmaxf(fmaxf(a3[0], a3[1]), a3[2])), a3[3]);
      }
      if (ctc < 15) {
#pragma unroll
        for (int cc = 0; cc < 4; ++cc) cu[cc] = cun[cc];
      }
    }
    // combine across quads (full rowmax per query col)
    bv0 = fmaxf(bv0, __shfl_xor(bv0, 16)); bv0 = fmaxf(bv0, __shfl_xor(bv0, 32));
    bv1 = fmaxf(bv1, __shfl_xor(bv1, 16)); bv1 = fmaxf(bv1, __shfl_xor(bv1, 32));
    bv2 = fmaxf(bv2, __shfl_xor(bv2, 16)); bv2 = fmaxf(bv2, __shfl_xor(bv2, 32));
    bv3 = fmaxf(bv3, __shfl_xor(bv3, 16)); bv3 = fmaxf(bv3, __shfl_xor(bv3, 32));
    // owner lanes (quad 0): mism[s][point] = rowmax > diag
    if (quad == 0) {
      mism[s][((qg & 3) * 4 + 0) * 16 + c15] = (bv0 > sdw[wv][0][c15]) ? 1 : 0;
      mism[s][((qg & 3) * 4 + 1) * 16 + c15] = (bv1 > sdw[wv][1][c15]) ? 1 : 0;
      mism[s][((qg & 3) * 4 + 2) * 16 + c15] = (bv2 > sdw[wv][2][c15]) ? 1 : 0;
      mism[s][((qg & 3) * 4 + 3) * 16 + c15] = (bv3 > sdw[wv][3][c15]) ? 1 : 0;
    }
  }
  __syncthreads();
  // ---- per point: m_p = first matching state; mask; cnt_k ------------------
  int mp = 8;
#pragma unroll
  for (int s = 0; s < 8; ++s) {
    if (mp == 8 && mism[s][tid] == 0) mp = s;
  }
  maskg[(b << 10) + n0 + tid] = (unsigned char)((1u << mp) - 1u);
#pragma unroll
  for (int k = 0; k < ITERS; ++k) {
    unsigned long long mk = __ballot(mp > k ? 1 : 0);
    if (lane == 0) atomicAdd(&cnt[k], (unsigned)__popcll(mk));
  }
  __syncthreads();
  if (tid < ITERS) cntg[tid * 512 + (int)blockIdx.x] = cnt[tid];
}

// ---- kernel 3: MLP + masked SE, with fused finalize (exact cont gate) ------
__global__ __launch_bounds__(256) void k_loss(
    const float* __restrict__ data, const float* __restrict__ noise0,
    const int* __restrict__ ts, const float* __restrict__ sacp,
    const float* __restrict__ s1m, const unsigned* __restrict__ keys,
    const unsigned* __restrict__ cntg, const unsigned char* __restrict__ maskg,
    const float* __restrict__ biasb,
    const float4* __restrict__ PA, const float4* __restrict__ PB,
    const float* __restrict__ PC, const float* __restrict__ b2,
    float* __restrict__ part) {
  __shared__ float4 sA[HID];
  __shared__ float4 sB[HID];
  __shared__ float2 sCb[HID];
  __shared__ float zn[256][6];     // z3..z5, noisy3..5 per local point
  __shared__ float pp[4][3][256];  // per-wave partials
  __shared__ float red[4];
  __shared__ int ksh;
  int b = blockIdx.x >> 2, qq = blockIdx.x & 3;
  int tid = (int)threadIdx.x;
  int wv = tid >> 6, lane = tid & 63;
  // ---- phase 1: kstar from cntg --------------------------------------------
  if (tid < 64) {
    int ks = ITERS;
    for (int k2 = 0; k2 < ITERS; ++k2) {
      unsigned v = 0u;
#pragma unroll
      for (int i = 0; i < 8; ++i) v += cntg[k2 * 512 + i * 64 + tid];
#pragma unroll
      for (int m = 32; m >= 1; m >>= 1) v += (unsigned)__shfl_xor((int)v, m);
      if (v < 10u && ks == ITERS) ks = k2;  // first failing iteration
    }
    if (tid == 0) ksh = ks;
  }
  // stage weights meanwhile
  for (int j = tid; j < HID; j += 256) {
    sA[j] = PA[j]; sB[j] = PB[j];
    sCb[j] = make_float2(PC[j], biasb[(size_t)b * HID + j]);
  }
  __syncthreads();
  // ---- phase 2: finalize this block's 256 points (1 per thread) ------------
  int p0 = (b << 10) + qq * 256;
  {
    int kstar = ksh;
    unsigned gate = (kstar >= ITERS) ? 0xFFu : ((1u << kstar) - 1u);
    int p = p0 + tid;
    int t = ts[b];
    float aa = sacp[t], ssv = s1m[t];
    unsigned m = (unsigned)maskg[p] & gate;
    float z3, z4, z5;
    if (m) {
      int j = 31 - __clz((int)m);  // last applied renoise iteration
      unsigned base6 = (unsigned)p * 6u;
      unsigned kk0 = keys[2*j], kk1 = keys[2*j+1];
      z3 = nrm_from_idx(kk0, kk1, base6 + 3u);
      z4 = nrm_from_idx(kk0, kk1, base6 + 4u);
      z5 = nrm_from_idx(kk0, kk1, base6 + 5u);
    } else {
      const float* np0 = noise0 + (size_t)p * 6;
      z3 = np0[3]; z4 = np0[4]; z5 = np0[5];
    }
    const float* dp = data + (size_t)p * 6;
    zn[tid][0] = z3; zn[tid][1] = z4; zn[tid][2] = z5;
    zn[tid][3] = __fadd_rn(__fmul_rn(aa, dp[3]), __fmul_rn(ssv, z3));
    zn[tid][4] = __fadd_rn(__fmul_rn(aa, dp[4]), __fmul_rn(ssv, z4));
    zn[tid][5] = __fadd_rn(__fmul_rn(aa, dp[5]), __fmul_rn(ssv, z5));
  }
  __syncthreads();
  // ---- phase 3: MLP, j-loop split across the 4 waves -----------------------
  float x[4][6];
  float a0[4], a1[4], a2[4];
#pragma unroll
  for (int q = 0; q < 4; ++q) {
    int pl = q * 64 + lane;
    int p = p0 + pl;
    x[q][0] = data[p*6+0]; x[q][1] = data[p*6+1]; x[q][2] = data[p*6+2];
    x[q][3] = zn[pl][3]; x[q][4] = zn[pl][4]; x[q][5] = zn[pl][5];
    a0[q] = 0.f; a1[q] = 0.f; a2[q] = 0.f;
  }
  int j0 = wv * 128;
#pragma unroll 2
  for (int jj = 0; jj < 128; ++jj) {
    int j = j0 + jj;
    float4 A = sA[j];
    float4 Bv = sB[j];
    float2 Cb = sCb[j];
#pragma unroll
    for (int q = 0; q < 4; ++q) {
      float s = x[q][0] * A.x;
      s = fmaf(x[q][1], A.y, s); s = fmaf(x[q][2], A.z, s);
      s = fmaf(x[q][3], A.w, s); s = fmaf(x[q][4], Bv.x, s);
      s = fmaf(x[q][5], Bv.y, s);
      s += Cb.y;
      float h = ftanh(s);
      a0[q] = fmaf(h, Bv.z, a0[q]);
      a1[q] = fmaf(h, Bv.w, a1[q]);
      a2[q] = fmaf(h, Cb.x, a2[q]);
    }
  }
#pragma unroll
  for (int q = 0; q < 4; ++q) {
    pp[wv][0][q * 64 + lane] = a0[q];
    pp[wv][1][q * 64 + lane] = a1[q];
    pp[wv][2][q * 64 + lane] = a2[q];
  }
  __syncthreads();
  float f0 = (pp[0][0][tid] + pp[1][0][tid] + pp[2][0][tid] + pp[3][0][tid])
             + b2[3] - zn[tid][0];
  float f1 = (pp[0][1][tid] + pp[1][1][tid] + pp[2][1][tid] + pp[3][1][tid])
             + b2[4] - zn[tid][1];
  float f2 = (pp[0][2][tid] + pp[1][2][tid] + pp[2][2][tid] + pp[3][2][tid])
             + b2[5] - zn[tid][2];
  float lsum = f0 * f0;
  lsum = fmaf(f1, f1, lsum);
  lsum = fmaf(f2, f2, lsum);
#pragma unroll
  for (int off = 32; off > 0; off >>= 1) lsum += __shfl_down(lsum, off);
  if ((tid & 63) == 0) red[tid >> 6] = lsum;
  __syncthreads();
  if (tid == 0) part[blockIdx.x] = red[0] + red[1] + red[2] + red[3];
}

// ---- kernel 4: final reduce ------------------------------------------------
__global__ void k_red(const float* __restrict__ part, float* __restrict__ out) {
  int b = (int)threadIdx.x;
  if (b < BS) {
    out[b] = (part[4*b] + part[4*b+1] + part[4*b+2] + part[4*b+3]) / 3072.0f;
  }
}

// ---------------------------------------------------------------------------
extern "C" void kernel_launch(void* const* d_in, const int* in_sizes, int n_in,
                              void* d_out, int out_size, void* d_ws, size_t ws_size,
                              hipStream_t stream) {
  (void)in_sizes; (void)n_in; (void)out_size; (void)ws_size;
  const float* data    = (const float*)d_in[0];
  const float* context = (const float*)d_in[1];
  const float* noise0  = (const float*)d_in[2];
  const float* W1      = (const float*)d_in[3];
  const float* Wc      = (const float*)d_in[4];
  const float* Wt      = (const float*)d_in[5];
  const float* b1      = (const float*)d_in[6];
  const float* W2      = (const float*)d_in[7];
  const float* b2      = (const float*)d_in[8];
  const int*   ts      = (const int*)d_in[9];
  float* out = (float*)d_out;

  char* w = (char*)d_ws;
  float*    sacp   = (float*)(w + OFF_SACP);
  float*    s1m    = (float*)(w + OFF_S1M);
  unsigned* keys   = (unsigned*)(w + OFF_KEYS);
  unsigned* cntg   = (unsigned*)(w + OFF_CNTG);
  unsigned char* maskg = (unsigned char*)(w + OFF_MASK);
  float*    biasb  = (float*)(w + OFF_BIAS);
  float4*   PA     = (float4*)(w + OFF_PA);
  float4*   PB     = (float4*)(w + OFF_PB);
  float*    PC     = (float*)(w + OFF_PC);
  float*    part   = (float*)(w + OFF_PART);

  k_setup<<<258, 256, 0, stream>>>(context, Wc, Wt, b1, ts, biasb,
                                   W1, W2, PA, PB, PC, sacp, s1m, keys);
  k_renoise<<<512, 256, 0, stream>>>(data, noise0, ts, sacp, s1m, keys,
                                     cntg, maskg);
  k_loss<<<512, 256, 0, stream>>>(data, noise0, ts, sacp, s1m, keys, cntg,
                                  maskg, biasb, PA, PB, PC, b2, part);
  k_red<<<1, 128, 0, stream>>>(part, out);
}